// Round 1
// baseline (8784.571 us; speedup 1.0000x reference)
//
#include <hip/hip_runtime.h>
#include <math.h>

// DCRNN encoder: T=24 steps x 2 layers of DCGRU over N=207 nodes, B=64, H=64, K=2 Chebyshev.
// Strategy: precompute S2 = 2*S@S once, so per gconv both diffusion hops come straight
// from x0 (no intermediate sync). One fused kernel per phase (gates / cand+update):
// block = (batch, 16-node tile); diffusion accumulated in registers, [x0|x1|x2] staged
// in LDS, dense matmul + activation + GRU epilogue fused.

constexpr int T_ = 24, B_ = 64, N_ = 207, IN_ = 2, H_ = 64;
constexpr int BNH = B_ * N_ * H_;          // 847872
constexpr int TN = 16;                      // nodes per block
constexpr int NT = (N_ + TN - 1) / TN;      // 13 tiles

// ---------------------------------------------------------------- S2 = 2*S@S
__global__ void s2_kernel(const float* __restrict__ S, float* __restrict__ S2) {
    const int n = blockIdx.x;
    const int m = threadIdx.x;
    if (m >= N_) return;
    float acc = 0.f;
    for (int k = 0; k < N_; ++k)
        acc += S[n * N_ + k] * S[k * N_ + m];
    S2[n * N_ + m] = 2.f * acc;
}

// ------------------------------------------------- init h0,h1 from input state
__global__ void init_h_kernel(const float* __restrict__ ih,
                              float* __restrict__ h0, float* __restrict__ h1) {
    int i = blockIdx.x * blockDim.x + threadIdx.x;
    if (i < BNH) { h0[i] = ih[i]; h1[i] = ih[BNH + i]; }
}

// --------------------------------------------------- final hidden-state copy
__global__ void final_copy_kernel(const float* __restrict__ h0,
                                  const float* __restrict__ h1,
                                  float* __restrict__ out_hid) {
    int i = blockIdx.x * blockDim.x + threadIdx.x;
    if (i < BNH) { out_hid[i] = h0[i]; out_hid[BNH + i] = h1[i]; }
}

// ------------------------------------------------------------- fused cell phase
// GATES (!IS_CAND): x0 = [inA | hpart(=h)], gates = sigmoid(xcat@W+b);
//                   writes out_a = r*h, out_b = u.
// CAND  (IS_CAND):  x0 = [inA | hpart(=rh)], c = tanh(xcat@W+b);
//                   h_new = u*h + (1-u)*c; writes out_a = h (in place),
//                   out_b = cur output (if WRITE_OUT).
template<int WA, bool IS_CAND, bool WRITE_OUT>
__global__ __launch_bounds__(128)
void cell_phase(const float* __restrict__ inA,    // [B, N, WA]
                const float* __restrict__ hpart,  // [B, N*H]  hidden part of x0
                const float* __restrict__ hbuf,   // [B, N*H]  current h
                const float* __restrict__ S,
                const float* __restrict__ S2,
                const float* __restrict__ W,      // [3D, O]
                const float* __restrict__ bias,   // [O]
                const float* __restrict__ ubuf,   // cand only
                float* __restrict__ out_a,
                float* __restrict__ out_b) {
    constexpr int D   = WA + H_;
    constexpr int KD  = 3 * D;
    constexpr int KDP = (KD + 3) & ~3;           // pad row stride to float4
    constexpr int O   = IS_CAND ? 64 : 128;

    __shared__ __align__(16) float sT[N_ * TN];   // sT[m*TN+i] = S[(n0+i)*N+m]
    __shared__ __align__(16) float s2T[N_ * TN];
    __shared__ __align__(16) float xc[TN * KDP];  // [x0 | x1 | x2] per tile row

    const int b   = blockIdx.y;
    const int n0  = blockIdx.x * TN;
    const int tid = threadIdx.x;

    // ---- stage S, S2 transposed tiles
    for (int idx = tid; idx < N_ * TN; idx += 128) {
        const int i = idx & (TN - 1);
        const int m = idx >> 4;
        const int n = n0 + i;
        float sv = 0.f, s2v = 0.f;
        if (n < N_) { sv = S[n * N_ + m]; s2v = S2[n * N_ + m]; }
        sT[idx] = sv; s2T[idx] = s2v;
    }
    __syncthreads();

    // ---- diffusion: thread d accumulates x1[i], x2raw[i] over all m
    if (tid < D) {
        const int d = tid;
        const float* xp;
        int stride;
        if (d < WA) { xp = inA + (size_t)(b * N_) * WA + d; stride = WA; }
        else        { xp = hpart + (size_t)(b * N_) * H_ + (d - WA); stride = H_; }

        float acc1[TN], acc2[TN];
#pragma unroll
        for (int i = 0; i < TN; ++i) { acc1[i] = 0.f; acc2[i] = 0.f; }

        for (int m = 0; m < N_; ++m) {
            const float xv = *xp; xp += stride;
            const float4* sp4  = reinterpret_cast<const float4*>(&sT[m * TN]);
            const float4* s2p4 = reinterpret_cast<const float4*>(&s2T[m * TN]);
#pragma unroll
            for (int q = 0; q < 4; ++q) {
                const float4 s  = sp4[q];
                const float4 s2 = s2p4[q];
                acc1[4*q+0] += s.x * xv;  acc2[4*q+0] += s2.x * xv;
                acc1[4*q+1] += s.y * xv;  acc2[4*q+1] += s2.y * xv;
                acc1[4*q+2] += s.z * xv;  acc2[4*q+2] += s2.z * xv;
                acc1[4*q+3] += s.w * xv;  acc2[4*q+3] += s2.w * xv;
            }
        }
#pragma unroll
        for (int i = 0; i < TN; ++i) {
            const int n  = n0 + i;
            const int nc = n < N_ ? n : N_ - 1;
            const float x0v = (d < WA) ? inA[(size_t)(b * N_ + nc) * WA + d]
                                       : hpart[(size_t)(b * N_ + nc) * H_ + (d - WA)];
            xc[i * KDP + d]         = x0v;
            xc[i * KDP + D + d]     = acc1[i];
            xc[i * KDP + 2 * D + d] = acc2[i] - x0v;
        }
    }
    __syncthreads();

    // ---- dense matmul [TN, KD] @ [KD, O]
    const int o     = tid % O;
    const int rbase = (tid / O) * (TN * O / 128);
    constexpr int RCNT = TN * O / 128;           // 16 (gates) or 8 (cand)

    float acc[RCNT];
#pragma unroll
    for (int r = 0; r < RCNT; ++r) acc[r] = 0.f;

    constexpr int K4 = KD & ~3;
    for (int k = 0; k < K4; k += 4) {
        const float w0 = W[(k + 0) * O + o];
        const float w1 = W[(k + 1) * O + o];
        const float w2 = W[(k + 2) * O + o];
        const float w3 = W[(k + 3) * O + o];
#pragma unroll
        for (int r = 0; r < RCNT; ++r) {
            const float4 xv = *reinterpret_cast<const float4*>(&xc[(rbase + r) * KDP + k]);
            acc[r] += xv.x * w0 + xv.y * w1 + xv.z * w2 + xv.w * w3;
        }
    }
    for (int k = K4; k < KD; ++k) {
        const float w = W[k * O + o];
#pragma unroll
        for (int r = 0; r < RCNT; ++r)
            acc[r] += xc[(rbase + r) * KDP + k] * w;
    }

    const float bv = bias[o];

    if (!IS_CAND) {
#pragma unroll
        for (int r = 0; r < RCNT; ++r) {
            const int n = n0 + rbase + r;
            if (n >= N_) continue;
            const size_t row = (size_t)(b * N_ + n);
            const float g = 1.f / (1.f + __expf(-(acc[r] + bv)));
            if (o < 64) out_a[row * 64 + o] = g * hbuf[row * 64 + o];  // r*h
            else        out_b[row * 64 + (o - 64)] = g;                // u
        }
    } else {
#pragma unroll
        for (int r = 0; r < RCNT; ++r) {
            const int n = n0 + rbase + r;
            if (n >= N_) continue;
            const size_t idx = (size_t)(b * N_ + n) * 64 + o;
            const float c  = tanhf(acc[r] + bv);
            const float uu = ubuf[idx];
            const float hn = uu * hbuf[idx] + (1.f - uu) * c;
            out_a[idx] = hn;
            if (WRITE_OUT) out_b[idx] = hn;
        }
    }
}

// ---------------------------------------------------------------------- launch
extern "C" void kernel_launch(void* const* d_in, const int* in_sizes, int n_in,
                              void* d_out, int out_size, void* d_ws, size_t ws_size,
                              hipStream_t stream) {
    const float* x   = (const float*)d_in[0];   // [T,B,N,IN]
    const float* ih  = (const float*)d_in[1];   // [2,B,N*H]
    const float* S   = (const float*)d_in[2];   // [1,N,N]
    const float* wg0 = (const float*)d_in[3];
    const float* bg0 = (const float*)d_in[4];
    const float* wc0 = (const float*)d_in[5];
    const float* bc0 = (const float*)d_in[6];
    const float* wg1 = (const float*)d_in[7];
    const float* bg1 = (const float*)d_in[8];
    const float* wc1 = (const float*)d_in[9];
    const float* bc1 = (const float*)d_in[10];

    float* ws = (float*)d_ws;
    float* S2 = ws;                      // 42849 floats (padded to 43008)
    float* h0 = ws + 43008;
    float* h1 = h0 + BNH;
    float* rh = h1 + BNH;
    float* ub = rh + BNH;

    float* out      = (float*)d_out;
    float* out_hid  = out;               // [2, B, N*H]
    float* out_cur  = out + 2 * (size_t)BNH;  // [T, B, N*H]

    init_h_kernel<<<(BNH + 255) / 256, 256, 0, stream>>>(ih, h0, h1);
    s2_kernel<<<N_, 256, 0, stream>>>(S, S2);

    const dim3 grid(NT, B_);
    for (int t = 0; t < T_; ++t) {
        const float* xt = x + (size_t)t * B_ * N_ * IN_;
        // layer 0
        cell_phase<IN_, false, false><<<grid, 128, 0, stream>>>(
            xt, h0, h0, S, S2, wg0, bg0, nullptr, rh, ub);
        cell_phase<IN_, true, false><<<grid, 128, 0, stream>>>(
            xt, rh, h0, S, S2, wc0, bc0, ub, h0, nullptr);
        // layer 1 (input = h0)
        cell_phase<H_, false, false><<<grid, 128, 0, stream>>>(
            h0, h1, h1, S, S2, wg1, bg1, nullptr, rh, ub);
        cell_phase<H_, true, true><<<grid, 128, 0, stream>>>(
            h0, rh, h1, S, S2, wc1, bc1, ub, h1, out_cur + (size_t)t * BNH);
    }

    final_copy_kernel<<<(BNH + 255) / 256, 256, 0, stream>>>(h0, h1, out_hid);
}

// Round 2
// 2356.944 us; speedup vs baseline: 3.7271x; 3.7271x over previous
//
#include <hip/hip_runtime.h>
#include <math.h>

// DCRNN encoder, MFMA restructure.
// Node-major layout [n][b][h]. Per phase: one stacked diffusion GEMM
// ([S;S2] @ X, bf16 MFMA) + one fused dense GEMM (+activation/GRU epilogue).
// S2=2*S@S precomputed; x2 = S2@x0 - x0 with "-x0" folded into W (W0' = W0-W2).
// Layer-0 x-part (IN=2) precomputed for all T; added in dense epilogue (VALU).
// Hidden state carried in f32; bf16 copies feed MFMA operands.

typedef unsigned short u16;
typedef unsigned int u32;
typedef short bf8 __attribute__((ext_vector_type(8)));   // 8 bf16 (MFMA operand)
typedef float f32x4 __attribute__((ext_vector_type(4)));
typedef u16 u16x8 __attribute__((ext_vector_type(8)));

constexpr int T_ = 24, B_ = 64, N_ = 207, H_ = 64;
constexpr int BH  = 4096;          // B*H cols (node-major row width)
constexpr int NBH = N_ * BH;       // 847872 (node-major state size)
constexpr int BNH = B_ * N_ * H_;  // 847872 (batch-major, output layout)

__device__ __forceinline__ float b2f(u16 b) {
    u32 u = ((u32)b) << 16; float f; __builtin_memcpy(&f, &u, 4); return f;
}
__device__ __forceinline__ u16 f2b(float f) {
    u32 u; __builtin_memcpy(&u, &f, 4);
    u32 r = (u + 0x7FFF + ((u >> 16) & 1)) >> 16;
    return (u16)r;
}

// ---------------------------------------------------------------- S2 = 2*S@S
__global__ void s2_kernel(const float* __restrict__ S, float* __restrict__ S2) {
    const int n = blockIdx.x, m = threadIdx.x;
    if (m >= N_) return;
    float acc = 0.f;
    for (int k = 0; k < N_; ++k) acc += S[n * N_ + k] * S[k * N_ + m];
    S2[n * N_ + m] = 2.f * acc;
}

// --------------------------------------------- A-operand blocks for diffusion
// ablk[half(S/S2)][rt 14][ks 7][kb 4][r 16][j 8] bf16, rows n=rt*16+r, k=ks*32+kb*8+j
__global__ void ablk_build(const float* __restrict__ S, const float* __restrict__ S2,
                           u16* __restrict__ ablk) {
    int idx = blockIdx.x * 256 + threadIdx.x;
    if (idx >= 2 * 14 * 7 * 4 * 16 * 8) return;
    int j = idx & 7, r = (idx >> 3) & 15, kb = (idx >> 7) & 3;
    int rest = idx >> 9;
    int ks = rest % 7; rest /= 7;
    int rt = rest % 14, half = rest / 14;
    int n = rt * 16 + r, k = ks * 32 + kb * 8 + j;
    float v = 0.f;
    if (n < N_ && k < N_) v = half ? S2[n * N_ + k] : S[n * N_ + k];
    ablk[idx] = f2b(v);
}

// ------------------------------------------------ W blocked to fragment order
// out[ks][kb][OF][j] bf16 ; k = ks*32+kb*8+j maps to W-row per layer layout;
// cheb-0 block folded: W0' = W0 - W2.
__global__ void wblk_build(const float* __restrict__ W, u16* __restrict__ out,
                           int OF, int total, int layer) {
    int idx = blockIdx.x * 256 + threadIdx.x;
    if (idx >= total) return;
    int j = idx & 7;
    int rest = idx >> 3;
    int o = rest % OF; rest /= OF;
    int kb = rest & 3, ks = rest >> 2;
    int k = ks * 32 + kb * 8 + j;
    int blk = k >> 6, d = k & 63;
    int wrow, wsub = -1;
    if (layer == 0) {                       // K-blocks: [x0h, x1h, x2h], D=66
        wrow = blk * 66 + 2 + d;
        if (blk == 0) wsub = 2 * 66 + 2 + d;
    } else {                                // [x0x,x0h,x1x,x1h,x2x,x2h], D=128
        int sb = blk >> 1, part = blk & 1;
        wrow = sb * 128 + part * 64 + d;
        if (sb == 0) wsub = 256 + part * 64 + d;
    }
    float v = W[wrow * OF + o];
    if (wsub >= 0) v -= W[wsub * OF + o];
    out[idx] = f2b(v);
}

// ------------------------------------- layer-0 x-feature weight slice (f32)
// wx[p 6][OF]: p = cheb*2 + i ; cheb0 folded.
__global__ void wx_build(const float* __restrict__ W, float* __restrict__ out, int OF) {
    int idx = blockIdx.x * 256 + threadIdx.x;
    if (idx >= 6 * OF) return;
    int o = idx % OF, p = idx / OF;
    int cheb = p >> 1, i = p & 1;
    float v = W[(cheb * 66 + i) * OF + o];
    if (cheb == 0) v -= W[(132 + i) * OF + o];
    out[idx] = v;
}

// ------------------------------------- x transpose: [T,B,N,2] -> [n][t][b][i]
__global__ void xt2_build(const float* __restrict__ x, u16* __restrict__ xt2) {
    int idx = blockIdx.x * 256 + threadIdx.x;
    if (idx >= N_ * T_ * B_ * 2) return;
    int i = idx & 1, b = (idx >> 1) & 63, rest = idx >> 7;
    int t = rest % T_, n = rest / T_;
    xt2[idx] = f2b(x[((t * B_ + b) * N_ + n) * 2 + i]);
}

// --------------------------------- layer-0 x diffusion for all T (VALU, tiny)
__global__ __launch_bounds__(256) void xd_build(const float* __restrict__ S,
                                                const float* __restrict__ S2,
                                                const u16* __restrict__ xt2,
                                                u16* __restrict__ xd0,
                                                u16* __restrict__ xd1) {
    __shared__ float sS[N_], sS2[N_];
    int n = blockIdx.x;
    int c = blockIdx.y * 256 + threadIdx.x;   // < 3072
    for (int i = threadIdx.x; i < N_; i += 256) { sS[i] = S[n*N_+i]; sS2[i] = S2[n*N_+i]; }
    __syncthreads();
    float a1 = 0.f, a2 = 0.f;
    for (int m = 0; m < N_; ++m) {
        float xv = b2f(xt2[m * 3072 + c]);
        a1 += sS[m] * xv; a2 += sS2[m] * xv;
    }
    xd0[(size_t)n * 3072 + c] = f2b(a1);
    xd1[(size_t)n * 3072 + c] = f2b(a2);
}

// ---------------------------------------------------------------- hidden init
__global__ void hinit_kernel(const float* __restrict__ ih, u16* __restrict__ h0b,
                             u16* __restrict__ h1b, float* __restrict__ h0f,
                             float* __restrict__ h1f) {
    int idx = blockIdx.x * 256 + threadIdx.x;  // [n][b][h]
    if (idx >= NBH) return;
    int h = idx & 63, b = (idx >> 6) & 63, n = idx >> 12;
    float v0 = ih[(size_t)b * (N_ * 64) + n * 64 + h];
    float v1 = ih[(size_t)BNH + (size_t)b * (N_ * 64) + n * 64 + h];
    h0b[idx] = f2b(v0); h1b[idx] = f2b(v1);
    h0f[idx] = v0;      h1f[idx] = v1;
}

// ---------------------------------------------------- diffusion GEMM (MFMA)
// out1 = S@X, out2 = S2@X ; X from srcA (col tiles < ctA, 64 cols each) or srcB.
// grid (ctA [*2 if dual], 14): y: half=by/7 (S vs S2 rows), rsub=by%7 (32 rows).
__global__ __launch_bounds__(256) void diff_kernel(
    const u16* __restrict__ ablk,
    const u16* __restrict__ srcA, const u16* __restrict__ srcB, int ctA,
    u16* __restrict__ dA1, u16* __restrict__ dA2,
    u16* __restrict__ dB1, u16* __restrict__ dB2) {
    __shared__ u16 sA[7168];     // [rt 2][ks 7][kb 4][r 16][j 8]
    __shared__ char sB[28672];   // [ks 7][m 32][64 cols] bf16, 128B pitch, XOR swz
    const int bx = blockIdx.x, by = blockIdx.y;
    const int half = by / 7, rsub = by % 7;
    const int tid = threadIdx.x;
    const u16* src; u16* dst1; u16* dst2; int c0;
    if (bx < ctA) { src = srcA; dst1 = dA1; dst2 = dA2; c0 = bx * 64; }
    else          { src = srcB; dst1 = dB1; dst2 = dB2; c0 = (bx - ctA) * 64; }

    const u16* ga = ablk + (size_t)(half * 14 + rsub * 2) * 3584;
    for (int i = tid; i < 896; i += 256)
        *(u16x8*)(sA + i * 8) = *(const u16x8*)(ga + i * 8);

    for (int id = tid; id < 1792; id += 256) {
        int ks = id >> 8, ch = id & 255;
        int ml = ch >> 3, cc = ch & 7;
        int m = ks * 32 + ml;
        u16x8 v = {0,0,0,0,0,0,0,0};
        if (m < N_) v = *(const u16x8*)(src + (size_t)m * 4096 + c0 + cc * 8);
        *(u16x8*)(sB + ks * 4096 + ((ml * 128 + cc * 16) ^ (((ml >> 3) & 3) << 5))) = v;
    }
    __syncthreads();

    const int w = tid >> 6, lane = tid & 63, lq = lane >> 4, lr = lane & 15;
    const int rt = w & 1, cfb = (w >> 1) * 2;
    f32x4 acc[2] = {{0,0,0,0},{0,0,0,0}};
    for (int ks = 0; ks < 7; ++ks) {
        bf8 a = *(const bf8*)(sA + ((((rt * 7) + ks) * 4 + lq) * 16 + lr) * 8);
#pragma unroll
        for (int cf = 0; cf < 2; ++cf) {
            int c = (cfb + cf) * 16 + lr;
            bf8 b;
#pragma unroll
            for (int j = 0; j < 8; ++j) {
                int m = lq * 8 + j;
                b[j] = *(const short*)(sB + ks * 4096 +
                        ((m * 128 + c * 2) ^ (((m >> 3) & 3) << 5)));
            }
            acc[cf] = __builtin_amdgcn_mfma_f32_16x16x32_bf16(a, b, acc[cf], 0, 0, 0);
        }
    }
    u16* dst = half ? dst2 : dst1;
#pragma unroll
    for (int cf = 0; cf < 2; ++cf) {
        int c = c0 + (cfb + cf) * 16 + lr;
#pragma unroll
        for (int j = 0; j < 4; ++j) {
            int n = rsub * 32 + rt * 16 + lq * 4 + j;
            if (n < N_) dst[(size_t)n * 4096 + c] = f2b(acc[cf][j]);
        }
    }
}

// -------------------------------------------------- dense GEMM + epilogue
// Per block: node n, O-half oh. [64 b, NBLK*64 k] @ [k, 64 o].
// gates: g=sigmoid(.); oh0 -> rh = g*h ; oh1 -> u = g.
// cand : c=tanh(.); h' = u*h + (1-u)*c -> bf16 + f32 (+ cur for layer 1).
template<int NBLK, int OF, bool XC, bool CAND, bool WCUR>
__global__ __launch_bounds__(256) void dense_kernel(
    const u16* __restrict__ s0, const u16* __restrict__ s1, const u16* __restrict__ s2v,
    const u16* __restrict__ s3, const u16* __restrict__ s4, const u16* __restrict__ s5,
    const u16* __restrict__ wblk, const float* __restrict__ bias,
    const float* __restrict__ hmul, float* __restrict__ ubuf,
    u16* __restrict__ outb, float* __restrict__ outf, float* __restrict__ cur,
    const u16* __restrict__ xt2, const u16* __restrict__ xd0,
    const u16* __restrict__ xd1, const float* __restrict__ wx, int t) {
    __shared__ char sAc[NBLK * 8192];   // per blk: [64 b][64 d] bf16, XOR swizzled
    const int n = blockIdx.x, oh = blockIdx.y, tid = threadIdx.x;
    const u16* const srcs[6] = {s0, s1, s2v, s3, s4, s5};
#pragma unroll
    for (int i = 0; i < NBLK; ++i) {
        const u16* sp = srcs[i] + (size_t)n * 4096;
        for (int id = tid; id < 512; id += 256) {
            int b = id >> 3, dc = id & 7;
            *(u16x8*)(sAc + i * 8192 + ((b * 128 + dc * 16) ^ ((b & 7) << 4))) =
                *(const u16x8*)(sp + b * 64 + dc * 8);
        }
    }
    __syncthreads();

    const int w = tid >> 6, lane = tid & 63, lq = lane >> 4, lr = lane & 15;
    const int ob = oh * 64;
    f32x4 acc[4] = {{0,0,0,0},{0,0,0,0},{0,0,0,0},{0,0,0,0}};
    for (int ks = 0; ks < 2 * NBLK; ++ks) {
        int blk = ks >> 1;
        int b = w * 16 + lr;
        bf8 a = *(const bf8*)(sAc + blk * 8192 +
                ((b * 128 + ((ks & 1) * 64 + lq * 16)) ^ ((b & 7) << 4)));
#pragma unroll
        for (int cf = 0; cf < 4; ++cf) {
            int o = ob + cf * 16 + lr;
            bf8 wv = *(const bf8*)(wblk + ((size_t)((ks * 4 + lq) * OF + o)) * 8);
            acc[cf] = __builtin_amdgcn_mfma_f32_16x16x32_bf16(a, wv, acc[cf], 0, 0, 0);
        }
    }

    float bv[4];
    float wxv[4][6];
#pragma unroll
    for (int cf = 0; cf < 4; ++cf) {
        bv[cf] = bias[ob + cf * 16 + lr];
        if (XC) {
#pragma unroll
            for (int p = 0; p < 6; ++p) wxv[cf][p] = wx[p * OF + ob + cf * 16 + lr];
        }
    }
#pragma unroll
    for (int j = 0; j < 4; ++j) {
        int b = w * 16 + lq * 4 + j;
        float xf[6];
        if (XC) {
            size_t cb = (size_t)n * 3072 + t * 128 + b * 2;
            xf[0] = b2f(xt2[cb]); xf[1] = b2f(xt2[cb + 1]);
            xf[2] = b2f(xd0[cb]); xf[3] = b2f(xd0[cb + 1]);
            xf[4] = b2f(xd1[cb]); xf[5] = b2f(xd1[cb + 1]);
        }
#pragma unroll
        for (int cf = 0; cf < 4; ++cf) {
            float v = acc[cf][j] + bv[cf];
            if (XC) {
#pragma unroll
                for (int p = 0; p < 6; ++p) v += xf[p] * wxv[cf][p];
            }
            int ol = cf * 16 + lr;
            size_t idx = (size_t)n * 4096 + b * 64 + ol;
            if (!CAND) {
                float g = 1.f / (1.f + __expf(-v));
                if (oh == 0) outb[idx] = f2b(g * hmul[idx]);
                else         ubuf[idx] = g;
            } else {
                float cc = tanhf(v);
                float uu = ubuf[idx];
                float hn = uu * hmul[idx] + (1.f - uu) * cc;
                outb[idx] = f2b(hn);
                outf[idx] = hn;
                if (WCUR) cur[((size_t)b * N_ + n) * 64 + ol] = hn;
            }
        }
    }
}

// ---------------------------------------------------------------- final copy
__global__ void final_kernel(const float* __restrict__ h0f,
                             const float* __restrict__ h1f,
                             float* __restrict__ out) {
    int idx = blockIdx.x * 256 + threadIdx.x;
    if (idx >= 2 * NBH) return;
    int l = idx / NBH, rem = idx % NBH;        // rem: [b][n][h]
    int h = rem & 63, nn = (rem >> 6) % N_, b = (rem >> 6) / N_;
    const float* src = l ? h1f : h0f;
    out[idx] = src[(size_t)nn * 4096 + b * 64 + h];
}

// ---------------------------------------------------------------------- launch
extern "C" void kernel_launch(void* const* d_in, const int* in_sizes, int n_in,
                              void* d_out, int out_size, void* d_ws, size_t ws_size,
                              hipStream_t stream) {
    const float* x   = (const float*)d_in[0];
    const float* ih  = (const float*)d_in[1];
    const float* S   = (const float*)d_in[2];
    const float* wg0 = (const float*)d_in[3];
    const float* bg0 = (const float*)d_in[4];
    const float* wc0 = (const float*)d_in[5];
    const float* bc0 = (const float*)d_in[6];
    const float* wg1 = (const float*)d_in[7];
    const float* bg1 = (const float*)d_in[8];
    const float* wc1 = (const float*)d_in[9];
    const float* bc1 = (const float*)d_in[10];

    char* p = (char*)d_ws;
    auto alloc = [&](size_t bytes) -> char* {
        char* r = p; p += (bytes + 255) & ~(size_t)255; return r;
    };
    float* S2    = (float*)alloc((size_t)N_ * N_ * 4);
    u16*   ablk  = (u16*)  alloc(100352 * 2);
    u16*   wg0b  = (u16*)  alloc(24576 * 2);
    u16*   wc0b  = (u16*)  alloc(12288 * 2);
    u16*   wg1b  = (u16*)  alloc(49152 * 2);
    u16*   wc1b  = (u16*)  alloc(24576 * 2);
    float* wxg0  = (float*)alloc(6 * 128 * 4);
    float* wxc0  = (float*)alloc(6 * 64 * 4);
    u16*   xt2   = (u16*)  alloc((size_t)N_ * 3072 * 2);
    u16*   xd0   = (u16*)  alloc((size_t)N_ * 3072 * 2);
    u16*   xd1   = (u16*)  alloc((size_t)N_ * 3072 * 2);
    u16*   h0init= (u16*)  alloc((size_t)NBH * 2);
    u16*   h0seq = (u16*)  alloc((size_t)T_ * NBH * 2);
    u16*   h1b   = (u16*)  alloc((size_t)NBH * 2);
    float* h0f   = (float*)alloc((size_t)NBH * 4);
    float* h1f   = (float*)alloc((size_t)NBH * 4);
    u16*   dbx1  = (u16*)  alloc((size_t)NBH * 2);
    u16*   dbx2  = (u16*)  alloc((size_t)NBH * 2);
    u16*   dbh1  = (u16*)  alloc((size_t)NBH * 2);
    u16*   dbh2  = (u16*)  alloc((size_t)NBH * 2);
    u16*   rh    = (u16*)  alloc((size_t)NBH * 2);
    float* u     = (float*)alloc((size_t)NBH * 4);

    float* out     = (float*)d_out;
    float* out_cur = out + 2 * (size_t)BNH;

    // ---- prep
    s2_kernel <<<N_, 256, 0, stream>>>(S, S2);
    ablk_build<<<392, 256, 0, stream>>>(S, S2, ablk);
    wblk_build<<<96, 256, 0, stream>>>(wg0, wg0b, 128, 24576, 0);
    wblk_build<<<48, 256, 0, stream>>>(wc0, wc0b,  64, 12288, 0);
    wblk_build<<<192, 256, 0, stream>>>(wg1, wg1b, 128, 49152, 1);
    wblk_build<<<96, 256, 0, stream>>>(wc1, wc1b,  64, 24576, 1);
    wx_build  <<<3, 256, 0, stream>>>(wg0, wxg0, 128);
    wx_build  <<<2, 256, 0, stream>>>(wc0, wxc0, 64);
    xt2_build <<<(N_ * T_ * B_ * 2 + 255) / 256, 256, 0, stream>>>(x, xt2);
    xd_build  <<<dim3(N_, 12), 256, 0, stream>>>(S, S2, xt2, xd0, xd1);
    hinit_kernel<<<(NBH + 255) / 256, 256, 0, stream>>>(ih, h0init, h1b, h0f, h1f);

    // ---- scan
    for (int t = 0; t < T_; ++t) {
        const u16* h0prevb = t ? h0seq + (size_t)(t - 1) * NBH : h0init;
        // ---- layer 0 gates
        diff_kernel<<<dim3(64, 14), 256, 0, stream>>>(
            ablk, h0prevb, h0prevb, 64, dbh1, dbh2, dbh1, dbh2);
        dense_kernel<3, 128, true, false, false><<<dim3(N_, 2), 256, 0, stream>>>(
            h0prevb, dbh1, dbh2, h0prevb, h0prevb, h0prevb, wg0b, bg0,
            h0f, u, rh, nullptr, nullptr, xt2, xd0, xd1, wxg0, t);
        // ---- layer 0 cand
        diff_kernel<<<dim3(64, 14), 256, 0, stream>>>(
            ablk, rh, rh, 64, dbh1, dbh2, dbh1, dbh2);
        dense_kernel<3, 64, true, true, false><<<dim3(N_, 1), 256, 0, stream>>>(
            rh, dbh1, dbh2, rh, rh, rh, wc0b, bc0,
            h0f, u, h0seq + (size_t)t * NBH, h0f, nullptr, xt2, xd0, xd1, wxc0, t);
        // ---- layer 1 gates
        const u16* h0tb = h0seq + (size_t)t * NBH;
        diff_kernel<<<dim3(128, 14), 256, 0, stream>>>(
            ablk, h0tb, h1b, 64, dbx1, dbx2, dbh1, dbh2);
        dense_kernel<6, 128, false, false, false><<<dim3(N_, 2), 256, 0, stream>>>(
            h0tb, h1b, dbx1, dbh1, dbx2, dbh2, wg1b, bg1,
            h1f, u, rh, nullptr, nullptr, nullptr, nullptr, nullptr, nullptr, 0);
        // ---- layer 1 cand
        diff_kernel<<<dim3(64, 14), 256, 0, stream>>>(
            ablk, rh, rh, 64, dbh1, dbh2, dbh1, dbh2);
        dense_kernel<6, 64, false, true, true><<<dim3(N_, 1), 256, 0, stream>>>(
            h0tb, rh, dbx1, dbh1, dbx2, dbh2, wc1b, bc1,
            h1f, u, h1b, h1f, out_cur + (size_t)t * BNH,
            nullptr, nullptr, nullptr, nullptr, 0);
    }

    final_kernel<<<(2 * NBH + 255) / 256, 256, 0, stream>>>(h0f, h1f, out);
}